// Round 1
// baseline (2434.355 us; speedup 1.0000x reference)
//
#include <hip/hip_runtime.h>
#include <math.h>

#define NB 256
#define NT 1024
#define ND 32
#define NH 64
#define NL 32
#define NW 64
#define G3 192
#define DT0 0.4f

__device__ __forceinline__ float sigm(float x) { return 1.0f / (1.0f + expf(-x)); }
// numerically stable softplus, matches jax.nn.softplus = log1p(exp(x))
__device__ __forceinline__ float softplusf(float x) {
    return fmaxf(x, 0.0f) + log1pf(expf(-fabsf(x)));
}

extern "C" __global__ void __launch_bounds__(256, 1)
latentode_fused(const float* __restrict__ ts,      // (B,T)
                const float* __restrict__ ys,      // (B,T,D)
                const float* __restrict__ eps,     // (B,L)
                const float* __restrict__ scale_p, // ()
                const float* __restrict__ fw0, const float* __restrict__ fb0,
                const float* __restrict__ fw1, const float* __restrict__ fb1,
                const float* __restrict__ fw2, const float* __restrict__ fb2,
                const float* __restrict__ gwi, const float* __restrict__ gwh,
                const float* __restrict__ gb,  const float* __restrict__ gbn,
                const float* __restrict__ hlw, const float* __restrict__ hlb,
                const float* __restrict__ lw0, const float* __restrict__ lb0,
                const float* __restrict__ lw1, const float* __restrict__ lb1,
                const float* __restrict__ lw2, const float* __restrict__ lb2,
                const float* __restrict__ hdw, const float* __restrict__ hdb,
                float* __restrict__ out)
{
    const int b   = blockIdx.x;
    const int tid = threadIdx.x;
    const int wv  = tid >> 6;
    const int ln  = tid & 63;

    __shared__ float xb[2][34];   // [t, y0..y31]
    __shared__ float hbuf[64];    // GRU hidden / reused
    __shared__ float g_rz[128];   // r,z preactivations (ig+hg)
    __shared__ float g_inn[64];
    __shared__ float g_hn[64];
    __shared__ float abuf0[64];
    __shared__ float abuf1[64];
    __shared__ float ybuf[64];    // ODE state
    __shared__ float lat[32];
    __shared__ float red[8];

    // ---------------- GRU phase ----------------
    float wiR[33];
    float whR[64];
    float gbias = 0.0f;
    if (tid < G3) {
#pragma unroll
        for (int k = 0; k < 33; ++k) wiR[k] = gwi[tid * 33 + k];
#pragma unroll
        for (int k = 0; k < 64; ++k) whR[k] = gwh[tid * 64 + k];
        gbias = gb[tid];
    }
    float bn_r = (tid < 64) ? gbn[tid] : 0.0f;

    if (tid < 64) hbuf[tid] = 0.0f;
    // prefetch x for s=0 (t = T-1)
    if (tid == 192) xb[0][0] = ts[b * NT + (NT - 1)];
    if (tid >= 193 && tid < 225) xb[0][1 + (tid - 193)] = ys[(b * NT + (NT - 1)) * ND + (tid - 193)];
    __syncthreads();

    for (int s = 0; s < NT; ++s) {
        const int cur = s & 1;
        const int nxt = cur ^ 1;
        if (tid < G3) {
            float acc_i = gbias;
#pragma unroll
            for (int k = 0; k < 33; ++k) acc_i += wiR[k] * xb[cur][k];
            float acc_h = 0.0f;
#pragma unroll
            for (int k = 0; k < 64; ++k) acc_h += whR[k] * hbuf[k];
            if (tid < 128) {
                g_rz[tid] = acc_i + acc_h;
            } else {
                g_inn[tid - 128] = acc_i;
                g_hn[tid - 128]  = acc_h;
            }
        } else if (s + 1 < NT) {
            const int t2 = NT - 2 - s;
            if (tid == 192) xb[nxt][0] = ts[b * NT + t2];
            else if (tid >= 193 && tid < 225) xb[nxt][1 + (tid - 193)] = ys[(b * NT + t2) * ND + (tid - 193)];
        }
        __syncthreads();
        if (tid < 64) {
            float r = sigm(g_rz[tid]);
            float z = sigm(g_rz[64 + tid]);
            float n = tanhf(g_inn[tid] + r * (g_hn[tid] + bn_r));
            float h = hbuf[tid];
            hbuf[tid] = n + z * (h - n);
        }
        __syncthreads();
    }

    // ---------------- context -> latent -> y0 ----------------
    float klpart = 0.0f;
    if (tid < 64) {
        float acc = hlb[tid];
#pragma unroll
        for (int k = 0; k < 64; ++k) acc += hlw[tid * 64 + k] * hbuf[k];
        abuf0[tid] = acc;  // context
    }
    __syncthreads();
    if (tid < 32) {
        float mean   = abuf0[tid];
        float logstd = abuf0[32 + tid];
        float stdv   = expf(logstd);
        lat[tid] = mean + eps[b * NL + tid] * stdv;
        klpart = 0.5f * (mean * mean + stdv * stdv - 2.0f * logstd - 1.0f);
    }
    __syncthreads();
    if (tid < 64) {
        float a = lb0[tid];
#pragma unroll
        for (int k = 0; k < 32; ++k) a += lw0[tid * 32 + k] * lat[k];
        abuf1[tid] = fmaxf(a, 0.0f);
    }
    __syncthreads();
    if (tid < 64) {
        float a = lb1[tid];
#pragma unroll
        for (int k = 0; k < 64; ++k) a += lw1[tid * 64 + k] * abuf1[k];
        hbuf[tid] = fmaxf(a, 0.0f);
    }
    __syncthreads();
    if (tid < 64) {
        float a = lb2[tid];
#pragma unroll
        for (int k = 0; k < 64; ++k) a += lw2[tid * 64 + k] * hbuf[k];
        ybuf[tid] = a;
    }
    __syncthreads();

    // ---------------- Euler ODE phase ----------------
    // wave0: layer0 (softplus), wave1: layer1 (softplus), wave2: layer2 (tanh) + y update,
    // wave3 lanes 0..31: hd projection + recon accumulation
    float wrow[64];
    float ebias = 0.0f;
    if (wv == 0) {
#pragma unroll
        for (int k = 0; k < 64; ++k) wrow[k] = fw0[ln * 64 + k];
        ebias = fb0[ln];
    } else if (wv == 1) {
#pragma unroll
        for (int k = 0; k < 64; ++k) wrow[k] = fw1[ln * 64 + k];
        ebias = fb1[ln];
    } else if (wv == 2) {
#pragma unroll
        for (int k = 0; k < 64; ++k) wrow[k] = fw2[ln * 64 + k];
        ebias = fb2[ln];
    } else if (ln < 32) {
#pragma unroll
        for (int k = 0; k < 64; ++k) wrow[k] = hdw[ln * 64 + k];
        ebias = hdb[ln];
    }
    const float scl = scale_p[0];
    const float dts = DT0 * scl;
    float recon = 0.0f;

    for (int s = 0; s < NT; ++s) {
        // phase A: layer0 from ybuf (y_s); wave3 pred from y_s (= ys_h[s-1]) for s>=1
        if (wv == 0) {
            float a = ebias;
#pragma unroll
            for (int k = 0; k < 64; ++k) a += wrow[k] * ybuf[k];
            abuf0[ln] = softplusf(a);
        } else if (wv == 3 && ln < 32 && s > 0) {
            float p = ebias;
#pragma unroll
            for (int k = 0; k < 64; ++k) p += wrow[k] * ybuf[k];
            float d = ys[(b * NT + (s - 1)) * ND + ln] - p;
            recon += d * d;
        }
        __syncthreads();
        if (wv == 1) {
            float a = ebias;
#pragma unroll
            for (int k = 0; k < 64; ++k) a += wrow[k] * abuf0[k];
            abuf1[ln] = softplusf(a);
        }
        __syncthreads();
        if (wv == 2) {
            float a = ebias;
#pragma unroll
            for (int k = 0; k < 64; ++k) a += wrow[k] * abuf1[k];
            ybuf[ln] = ybuf[ln] + dts * tanhf(a);
        }
        __syncthreads();
    }
    // epilogue: pred for final state y_T (= ys_h[T-1])
    if (wv == 3 && ln < 32) {
        float p = ebias;
#pragma unroll
        for (int k = 0; k < 64; ++k) p += wrow[k] * ybuf[k];
        float d = ys[(b * NT + (NT - 1)) * ND + ln] - p;
        recon += d * d;
    }

    // ---------------- final reduction ----------------
    float klv = klpart;
#pragma unroll
    for (int off = 32; off > 0; off >>= 1) klv += __shfl_xor(klv, off);
    if (tid == 0) red[0] = klv;

    float rv = recon;
#pragma unroll
    for (int off = 32; off > 0; off >>= 1) rv += __shfl_xor(rv, off);
    if (tid == 192) red[1] = rv;
    __syncthreads();

    if (tid == 0) out[b] = 0.5f * red[1] + red[0];
}

extern "C" void kernel_launch(void* const* d_in, const int* in_sizes, int n_in,
                              void* d_out, int out_size, void* d_ws, size_t ws_size,
                              hipStream_t stream) {
    const float* ts      = (const float*)d_in[0];
    const float* ys      = (const float*)d_in[1];
    const float* eps     = (const float*)d_in[2];
    const float* scale_p = (const float*)d_in[3];
    const float* fw0     = (const float*)d_in[4];
    const float* fb0     = (const float*)d_in[5];
    const float* fw1     = (const float*)d_in[6];
    const float* fb1     = (const float*)d_in[7];
    const float* fw2     = (const float*)d_in[8];
    const float* fb2     = (const float*)d_in[9];
    const float* gwi     = (const float*)d_in[10];
    const float* gwh     = (const float*)d_in[11];
    const float* gbv     = (const float*)d_in[12];
    const float* gbn     = (const float*)d_in[13];
    const float* hlw     = (const float*)d_in[14];
    const float* hlb     = (const float*)d_in[15];
    const float* lw0     = (const float*)d_in[16];
    const float* lb0     = (const float*)d_in[17];
    const float* lw1     = (const float*)d_in[18];
    const float* lb1     = (const float*)d_in[19];
    const float* lw2     = (const float*)d_in[20];
    const float* lb2     = (const float*)d_in[21];
    const float* hdw     = (const float*)d_in[22];
    const float* hdb     = (const float*)d_in[23];
    float* out = (float*)d_out;

    dim3 grid(NB);
    dim3 block(256);
    hipLaunchKernelGGL(latentode_fused, grid, block, 0, stream,
                       ts, ys, eps, scale_p, fw0, fb0, fw1, fb1, fw2, fb2,
                       gwi, gwh, gbv, gbn, hlw, hlb, lw0, lb0, lw1, lb1,
                       lw2, lb2, hdw, hdb, out);
}

// Round 2
// 1523.327 us; speedup vs baseline: 1.5981x; 1.5981x over previous
//
#include <hip/hip_runtime.h>
#include <math.h>

#define NB 256
#define NT 1024
#define ND 32
#define NH 64
#define NL 32
#define DT0 0.4f

__device__ __forceinline__ float dot4(float4 a, float4 b) {
    return a.x * b.x + a.y * b.y + a.z * b.z + a.w * b.w;
}
__device__ __forceinline__ float fsigm(float x) {
    return __fdividef(1.0f, 1.0f + __expf(-x));
}
__device__ __forceinline__ float ftanh(float x) {
    float cx = fminf(fmaxf(x, -15.0f), 15.0f);
    float e2 = __expf(2.0f * cx);
    return __fdividef(e2 - 1.0f, e2 + 1.0f);
}
__device__ __forceinline__ float fsoftplus(float x) {
    return fmaxf(x, 0.0f) + __logf(1.0f + __expf(-fabsf(x)));
}

// load wi row (33 floats, only 4B-aligned): [0]=ts weight, [1..32]=y weights
#define LDROW(A, g) do { \
    A##0 = make_float4((g)[1],(g)[2],(g)[3],(g)[4]); \
    A##1 = make_float4((g)[5],(g)[6],(g)[7],(g)[8]); \
    A##2 = make_float4((g)[9],(g)[10],(g)[11],(g)[12]); \
    A##3 = make_float4((g)[13],(g)[14],(g)[15],(g)[16]); \
    A##4 = make_float4((g)[17],(g)[18],(g)[19],(g)[20]); \
    A##5 = make_float4((g)[21],(g)[22],(g)[23],(g)[24]); \
    A##6 = make_float4((g)[25],(g)[26],(g)[27],(g)[28]); \
    A##7 = make_float4((g)[29],(g)[30],(g)[31],(g)[32]); \
} while (0)

extern "C" __global__ void __launch_bounds__(256, 1)
latentode_fused(const float* __restrict__ ts,      // (B,T)
                const float* __restrict__ ys,      // (B,T,D)
                const float* __restrict__ eps,     // (B,L)
                const float* __restrict__ scale_p, // ()
                const float* __restrict__ fw0, const float* __restrict__ fb0,
                const float* __restrict__ fw1, const float* __restrict__ fb1,
                const float* __restrict__ fw2, const float* __restrict__ fb2,
                const float* __restrict__ gwi, const float* __restrict__ gwh,
                const float* __restrict__ gb,  const float* __restrict__ gbn,
                const float* __restrict__ hlw, const float* __restrict__ hlb,
                const float* __restrict__ lw0, const float* __restrict__ lb0,
                const float* __restrict__ lw1, const float* __restrict__ lb1,
                const float* __restrict__ lw2, const float* __restrict__ lb2,
                const float* __restrict__ hdw, const float* __restrict__ hdb,
                float* __restrict__ out)
{
    const int b   = blockIdx.x;
    const int tid = threadIdx.x;

    // x chunk ring: 2 chunks x 4 steps x (32 y + 1 ts + pad) floats
    __shared__ __align__(16) float xc[2][4][36];
    __shared__ __align__(16) float hbuf[64];
    __shared__ __align__(16) float hacc[192];
    __shared__ __align__(16) float abuf0[64];
    __shared__ __align__(16) float abuf1[64];
    __shared__ __align__(16) float tbuf[64];
    __shared__ __align__(16) float ybuf[64];
    __shared__ __align__(16) float lat[32];
    __shared__ float redr[32];

    // ================= GRU weight loads (named regs, no arrays) =================
    // threads 0..191: wh row tid (64 floats, 256B aligned)
    float4 W0,W1,W2,W3,W4,W5,W6,W7,W8,W9,W10,W11,W12,W13,W14,W15;
    {
        const int r = (tid < 192) ? tid : 0;
        const float4* wp = (const float4*)(gwh + r * 64);
        W0=wp[0];  W1=wp[1];  W2=wp[2];  W3=wp[3];
        W4=wp[4];  W5=wp[5];  W6=wp[6];  W7=wp[7];
        W8=wp[8];  W9=wp[9];  W10=wp[10];W11=wp[11];
        W12=wp[12];W13=wp[13];W14=wp[14];W15=wp[15];
    }
    // wave3 (tid>=192): wi rows j, 64+j, 128+j (scalar loads; rows only 4B aligned)
    const int j3 = tid & 63;
    float4 P0,P1,P2,P3,P4,P5,P6,P7;
    float4 Q0,Q1,Q2,Q3,Q4,Q5,Q6,Q7;
    float4 R0,R1,R2,R3,R4,R5,R6,R7;
    float Pt=0.f, Qt=0.f, Rt=0.f, gbr=0.f, gbz=0.f, gbnb=0.f, bnv=0.f;
    if (tid >= 192) {
        const float* gr = gwi + j3 * 33;
        const float* gz = gwi + (64 + j3) * 33;
        const float* gn = gwi + (128 + j3) * 33;
        Pt = gr[0]; Qt = gz[0]; Rt = gn[0];
        LDROW(P, gr); LDROW(Q, gz); LDROW(R, gn);
        gbr = gb[j3]; gbz = gb[64 + j3]; gbnb = gb[128 + j3];
        bnv = gbn[j3];
    }

    // ================= prologue: h=0, stage chunk 0 (t = 1023..1020) ============
    if (tid < 64) hbuf[tid] = 0.0f;
    if (tid < 128) {
        const int ii = tid >> 5, col = tid & 31;
        xc[0][ii][col] = ys[(b * NT + (NT - 1 - ii)) * ND + col];
    } else if (tid < 132) {
        const int ii = tid - 128;
        xc[0][ii][32] = ts[b * NT + (NT - 1 - ii)];
    }
    __syncthreads();

    // ================= GRU scan (backward over t) ===============================
    float hreg = 0.0f;          // wave3: h[j3]
    float prefy = 0.0f, preft = 0.0f;
    float xrg = 0.0f, xzg = 0.0f, xng = 0.0f;

    for (int s = 0; s < NT; ++s) {
        const int cb = (s >> 2) & 1;
        const int ir = s & 3;

        // issue next-chunk global loads at chunk start (slack ~4 steps)
        if (ir == 0) {
            const int c1 = (s >> 2) + 1;
            if (c1 < (NT >> 2)) {
                const int tb = NT - 1 - 4 * c1;
                if (tid < 128) {
                    const int ii = tid >> 5, col = tid & 31;
                    prefy = ys[(b * NT + (tb - ii)) * ND + col];
                } else if (tid < 132) {
                    preft = ts[b * NT + (tb - (tid - 128))];
                }
            }
        }

        if (tid < 192) {
            // h-dot: 64 FMAs, 4 accumulators, broadcast LDS reads
            const float4* hv = (const float4*)hbuf;
            float4 h0=hv[0],h1=hv[1],h2=hv[2],h3=hv[3],h4=hv[4],h5=hv[5],h6=hv[6],h7=hv[7];
            float4 h8=hv[8],h9=hv[9],h10=hv[10],h11=hv[11],h12=hv[12],h13=hv[13],h14=hv[14],h15=hv[15];
            float a0 = dot4(W0,h0) + dot4(W4,h4) + dot4(W8,h8)  + dot4(W12,h12);
            float a1 = dot4(W1,h1) + dot4(W5,h5) + dot4(W9,h9)  + dot4(W13,h13);
            float a2 = dot4(W2,h2) + dot4(W6,h6) + dot4(W10,h10)+ dot4(W14,h14);
            float a3 = dot4(W3,h3) + dot4(W7,h7) + dot4(W11,h11)+ dot4(W15,h15);
            hacc[tid] = (a0 + a1) + (a2 + a3);
        } else {
            // x-dots for the 3 gate rows of unit j3
            const float* xrow = &xc[cb][ir][0];
            const float4* xv = (const float4*)xrow;
            float4 x0=xv[0],x1=xv[1],x2=xv[2],x3=xv[3],x4=xv[4],x5=xv[5],x6=xv[6],x7=xv[7];
            const float tsv = xrow[32];
            float pA = gbr + Pt * tsv + dot4(P0,x0) + dot4(P2,x2) + dot4(P4,x4) + dot4(P6,x6);
            float pB = dot4(P1,x1) + dot4(P3,x3) + dot4(P5,x5) + dot4(P7,x7);
            xrg = pA + pB;
            float qA = gbz + Qt * tsv + dot4(Q0,x0) + dot4(Q2,x2) + dot4(Q4,x4) + dot4(Q6,x6);
            float qB = dot4(Q1,x1) + dot4(Q3,x3) + dot4(Q5,x5) + dot4(Q7,x7);
            xzg = qA + qB;
            float rA = gbnb + Rt * tsv + dot4(R0,x0) + dot4(R2,x2) + dot4(R4,x4) + dot4(R6,x6);
            float rB = dot4(R1,x1) + dot4(R3,x3) + dot4(R5,x5) + dot4(R7,x7);
            xng = rA + rB;
        }
        __syncthreads();

        if (tid >= 192) {
            const float hr_ = hacc[j3], hz_ = hacc[64 + j3], hn_ = hacc[128 + j3];
            const float rg = fsigm(xrg + hr_);
            const float zg = fsigm(xzg + hz_);
            const float ng = ftanh(xng + rg * (hn_ + bnv));
            hreg = ng + zg * (hreg - ng);
            hbuf[j3] = hreg;
        } else if (ir == 3) {
            const int c1 = (s >> 2) + 1;
            if (c1 < (NT >> 2)) {
                if (tid < 128)      xc[c1 & 1][tid >> 5][tid & 31] = prefy;
                else if (tid < 132) xc[c1 & 1][tid - 128][32]      = preft;
            }
        }
        __syncthreads();
    }

    // ================= context -> latent -> y0 ==================================
    if (tid < 64) {
        const float4* wp = (const float4*)(hlw + tid * 64);
        const float4* hv = (const float4*)hbuf;
        float a0 = hlb[tid], a1 = 0.0f;
#pragma unroll
        for (int q = 0; q < 16; q += 2) { a0 += dot4(wp[q], hv[q]); a1 += dot4(wp[q+1], hv[q+1]); }
        abuf0[tid] = a0 + a1;
    }
    __syncthreads();
    float klpart = 0.0f;
    if (tid < 32) {
        const float mean   = abuf0[tid];
        const float logstd = abuf0[32 + tid];
        const float stdv   = __expf(logstd);
        lat[tid] = mean + eps[b * NL + tid] * stdv;
        klpart = 0.5f * (mean * mean + stdv * stdv - 2.0f * logstd - 1.0f);
    }
    __syncthreads();
    if (tid < 64) {
        const float4* wp = (const float4*)(lw0 + tid * 32);
        const float4* lv = (const float4*)lat;
        float a0 = lb0[tid], a1 = 0.0f;
#pragma unroll
        for (int q = 0; q < 8; q += 2) { a0 += dot4(wp[q], lv[q]); a1 += dot4(wp[q+1], lv[q+1]); }
        abuf1[tid] = fmaxf(a0 + a1, 0.0f);
    }
    __syncthreads();
    if (tid < 64) {
        const float4* wp = (const float4*)(lw1 + tid * 64);
        const float4* av = (const float4*)abuf1;
        float a0 = lb1[tid], a1 = 0.0f;
#pragma unroll
        for (int q = 0; q < 16; q += 2) { a0 += dot4(wp[q], av[q]); a1 += dot4(wp[q+1], av[q+1]); }
        tbuf[tid] = fmaxf(a0 + a1, 0.0f);
    }
    __syncthreads();
    if (tid < 64) {
        const float4* wp = (const float4*)(lw2 + tid * 64);
        const float4* tv = (const float4*)tbuf;
        float a0 = lb2[tid], a1 = 0.0f;
#pragma unroll
        for (int q = 0; q < 16; q += 2) { a0 += dot4(wp[q], tv[q]); a1 += dot4(wp[q+1], tv[q+1]); }
        ybuf[tid] = a0 + a1;
    }

    // ================= Euler weights (named regs) ===============================
    const int er = tid >> 2, ep = tid & 3;     // 64 rows x 4-way k-split
    const float4* p0 = (const float4*)(fw0 + er * 64 + ep * 16);
    float4 E00=p0[0],E01=p0[1],E02=p0[2],E03=p0[3];
    const float4* p1 = (const float4*)(fw1 + er * 64 + ep * 16);
    float4 E10=p1[0],E11=p1[1],E12=p1[2],E13=p1[3];
    const float4* p2 = (const float4*)(fw2 + er * 64 + ep * 16);
    float4 E20=p2[0],E21=p2[1],E22=p2[2],E23=p2[3];
    const int hr2 = tid >> 3, hp = tid & 7;    // 32 rows x 8-way k-split
    const float4* ph = (const float4*)(hdw + hr2 * 64 + hp * 8);
    float4 HD0=ph[0], HD1=ph[1];
    const float eb0 = fb0[er], eb1 = fb1[er], eb2 = fb2[er], hbb = hdb[hr2];
    const float dts = DT0 * scale_p[0];
    float ydA = ys[(b * NT + 0) * ND + hr2];   // ys row s-1 FIFO (2-deep)
    float ydB = ys[(b * NT + 1) * ND + hr2];
    float rec = 0.0f;
    __syncthreads();

    // ================= Euler scan ===============================================
    for (int s = 0; s < NT; ++s) {
        // ---- phase A: layer0 + hd projection (both read ybuf = y_s) ----
        const float4* yv = (const float4*)ybuf;
        {
            float4 ya=yv[ep*4+0], yb=yv[ep*4+1], yc=yv[ep*4+2], yd=yv[ep*4+3];
            float lA = dot4(E00,ya) + dot4(E02,yc);
            float lB = dot4(E01,yb) + dot4(E03,yd);
            float l0 = lA + lB;
            l0 += __shfl_xor(l0, 1);
            l0 += __shfl_xor(l0, 2);
            const float act0 = fsoftplus(l0 + eb0);

            float4 za=yv[hp*2+0], zb=yv[hp*2+1];
            float phd = dot4(HD0, za) + dot4(HD1, zb);
            phd += __shfl_xor(phd, 1);
            phd += __shfl_xor(phd, 2);
            phd += __shfl_xor(phd, 4);
            if (hp == 0 && s > 0) {
                const float d = ydA - (phd + hbb);
                rec += d * d;
                ydA = ydB;
                if (s + 1 < NT) ydB = ys[(b * NT + (s + 1)) * ND + hr2];
            }
            if (ep == 0) abuf0[er] = act0;
        }
        __syncthreads();
        // ---- phase B: layer1 ----
        {
            const float4* av = (const float4*)abuf0;
            float4 aa=av[ep*4+0], ab=av[ep*4+1], ac=av[ep*4+2], ad=av[ep*4+3];
            float mA = dot4(E10,aa) + dot4(E12,ac);
            float mB = dot4(E11,ab) + dot4(E13,ad);
            float l1 = mA + mB;
            l1 += __shfl_xor(l1, 1);
            l1 += __shfl_xor(l1, 2);
            const float act1 = fsoftplus(l1 + eb1);
            if (ep == 0) abuf1[er] = act1;
        }
        __syncthreads();
        // ---- phase C: layer2 + y update ----
        {
            const float4* bv = (const float4*)abuf1;
            float4 ba=bv[ep*4+0], bb=bv[ep*4+1], bc=bv[ep*4+2], bd=bv[ep*4+3];
            float nA = dot4(E20,ba) + dot4(E22,bc);
            float nB = dot4(E21,bb) + dot4(E23,bd);
            float l2 = nA + nB;
            l2 += __shfl_xor(l2, 1);
            l2 += __shfl_xor(l2, 2);
            const float tv = ftanh(l2 + eb2);
            if (ep == 0) ybuf[er] += dts * tv;
        }
        __syncthreads();
    }

    // ---- epilogue: pred for final state y_T vs ys[T-1] ----
    {
        const float4* yv = (const float4*)ybuf;
        float4 za=yv[hp*2+0], zb=yv[hp*2+1];
        float phd = dot4(HD0, za) + dot4(HD1, zb);
        phd += __shfl_xor(phd, 1);
        phd += __shfl_xor(phd, 2);
        phd += __shfl_xor(phd, 4);
        if (hp == 0) {
            const float d = ydA - (phd + hbb);
            rec += d * d;
            redr[hr2] = rec;
        }
    }
    // KL reduce (nonzero only in lanes tid<32, all in wave 0)
    float klv = klpart;
    klv += __shfl_xor(klv, 1);
    klv += __shfl_xor(klv, 2);
    klv += __shfl_xor(klv, 4);
    klv += __shfl_xor(klv, 8);
    klv += __shfl_xor(klv, 16);
    klv += __shfl_xor(klv, 32);
    __syncthreads();
    if (tid == 0) {
        float rs = 0.0f;
#pragma unroll
        for (int k2 = 0; k2 < 32; ++k2) rs += redr[k2];
        out[b] = 0.5f * rs + klv;
    }
}

extern "C" void kernel_launch(void* const* d_in, const int* in_sizes, int n_in,
                              void* d_out, int out_size, void* d_ws, size_t ws_size,
                              hipStream_t stream) {
    (void)in_sizes; (void)n_in; (void)out_size; (void)d_ws; (void)ws_size;
    const float* ts      = (const float*)d_in[0];
    const float* ys      = (const float*)d_in[1];
    const float* eps     = (const float*)d_in[2];
    const float* scale_p = (const float*)d_in[3];
    const float* fw0     = (const float*)d_in[4];
    const float* fb0     = (const float*)d_in[5];
    const float* fw1     = (const float*)d_in[6];
    const float* fb1     = (const float*)d_in[7];
    const float* fw2     = (const float*)d_in[8];
    const float* fb2     = (const float*)d_in[9];
    const float* gwi     = (const float*)d_in[10];
    const float* gwh     = (const float*)d_in[11];
    const float* gbv     = (const float*)d_in[12];
    const float* gbn     = (const float*)d_in[13];
    const float* hlw     = (const float*)d_in[14];
    const float* hlb     = (const float*)d_in[15];
    const float* lw0     = (const float*)d_in[16];
    const float* lb0     = (const float*)d_in[17];
    const float* lw1     = (const float*)d_in[18];
    const float* lb1     = (const float*)d_in[19];
    const float* lw2     = (const float*)d_in[20];
    const float* lb2     = (const float*)d_in[21];
    const float* hdw     = (const float*)d_in[22];
    const float* hdb     = (const float*)d_in[23];
    float* out = (float*)d_out;

    hipLaunchKernelGGL(latentode_fused, dim3(NB), dim3(256), 0, stream,
                       ts, ys, eps, scale_p, fw0, fb0, fw1, fb1, fw2, fb2,
                       gwi, gwh, gbv, gbn, hlw, hlb, lw0, lb0, lw1, lb1,
                       lw2, lb2, hdw, hdb, out);
}